// Round 3
// baseline (5590.454 us; speedup 1.0000x reference)
//
#include <hip/hip_runtime.h>

// DMPNN: N=50000, E=1.2M directed edges (pairs interleaved: rev(e)=e^1), DIM=64, STEPS=4.
// Round 3: fp32, W-in-registers, float4 broadcast LDS reads, per-wave staging (no barriers),
// scatter fused into producer kernels (ping-pong agg buffers), init writes h0 only.
//
// d_out = [ node_out (N*64) | h (E*64) ] f32.
// d_ws  = [ aggA (N*64) | aggB (N*64) | h0 (E*64) ] f32.

#define DIM 64

// ---- init: h0[e] = relu([nf[src]||ef] @ W + b); atomicAdd aggA[dst] += h0 ----
__global__ __launch_bounds__(256) void k_init(
    const float* __restrict__ nf, const float* __restrict__ ef,
    const int* __restrict__ src, const int* __restrict__ dst,
    const float* __restrict__ W, const float* __restrict__ b,
    float* __restrict__ h0, float* __restrict__ aggA, int E) {
  __shared__ float ins[4][4][2 * DIM];  // per-wave private: [wave][edge][128]
  const int tid = threadIdx.x, wave = tid >> 6, lane = tid & 63;
  float wcol[128];
  #pragma unroll
  for (int k = 0; k < 128; ++k) wcol[k] = W[k * 64 + lane];
  const float bl = b[lane];
  for (int base = blockIdx.x * 16 + wave * 4; base < E; base += gridDim.x * 16) {
    int dArr[4];
    #pragma unroll
    for (int j = 0; j < 4; ++j) {
      const int e = base + j;
      if (e < E) {
        const int s = src[e];
        dArr[j] = dst[e];
        ins[wave][j][lane]       = nf[(size_t)s * DIM + lane];
        ins[wave][j][DIM + lane] = ef[(size_t)e * DIM + lane];
      }
    }
    float acc[4] = {bl, bl, bl, bl};
    const float4* q0 = (const float4*)ins[wave][0];
    const float4* q1 = (const float4*)ins[wave][1];
    const float4* q2 = (const float4*)ins[wave][2];
    const float4* q3 = (const float4*)ins[wave][3];
    #pragma unroll
    for (int k4 = 0; k4 < 32; ++k4) {
      const float4 i0 = q0[k4], i1 = q1[k4], i2 = q2[k4], i3 = q3[k4];
      const float w0 = wcol[4*k4], w1 = wcol[4*k4+1], w2 = wcol[4*k4+2], w3 = wcol[4*k4+3];
      acc[0] = fmaf(i0.x, w0, acc[0]); acc[1] = fmaf(i1.x, w0, acc[1]);
      acc[2] = fmaf(i2.x, w0, acc[2]); acc[3] = fmaf(i3.x, w0, acc[3]);
      acc[0] = fmaf(i0.y, w1, acc[0]); acc[1] = fmaf(i1.y, w1, acc[1]);
      acc[2] = fmaf(i2.y, w1, acc[2]); acc[3] = fmaf(i3.y, w1, acc[3]);
      acc[0] = fmaf(i0.z, w2, acc[0]); acc[1] = fmaf(i1.z, w2, acc[1]);
      acc[2] = fmaf(i2.z, w2, acc[2]); acc[3] = fmaf(i3.z, w2, acc[3]);
      acc[0] = fmaf(i0.w, w3, acc[0]); acc[1] = fmaf(i1.w, w3, acc[1]);
      acc[2] = fmaf(i2.w, w3, acc[2]); acc[3] = fmaf(i3.w, w3, acc[3]);
    }
    #pragma unroll
    for (int j = 0; j < 4; ++j) {
      const int e = base + j;
      if (e < E) {
        const float v = fmaxf(acc[j], 0.0f);
        h0[(size_t)e * DIM + lane] = v;
        atomicAdd(&aggA[(size_t)dArr[j] * DIM + lane], v);
      }
    }
  }
}

// ---- step: per pair: m = agg[src] - h[rev]; hn = relu(h0 + m@W + b); scatter hn -> aggN ----
__global__ __launch_bounds__(256) void k_step(
    const float* __restrict__ agg, const int* __restrict__ src,
    const float* __restrict__ h0, const float* __restrict__ W, const float* __restrict__ b,
    const float* __restrict__ hin, float* __restrict__ hout,
    float* __restrict__ aggN, int E) {
  __shared__ float ins[4][8][DIM];  // [wave][edge-in-4-pairs][64]
  const int tid = threadIdx.x, wave = tid >> 6, lane = tid & 63;
  float wcol[64];
  #pragma unroll
  for (int k = 0; k < 64; ++k) wcol[k] = W[k * 64 + lane];
  const float bl = b[lane];
  const int P = E >> 1;  // rev(2p)=2p+1
  for (int base = blockIdx.x * 16 + wave * 4; base < P; base += gridDim.x * 16) {
    int s0a[4], s1a[4];
    #pragma unroll
    for (int j = 0; j < 4; ++j) {
      const int p = base + j;
      if (p < P) {
        const size_t e0 = (size_t)2 * p;
        const int s0 = src[e0], s1 = src[e0 + 1];
        s0a[j] = s0; s1a[j] = s1;
        const float hv0 = hin[e0 * DIM + lane];
        const float hv1 = hin[e0 * DIM + DIM + lane];
        ins[wave][2*j][lane]     = agg[(size_t)s0 * DIM + lane] - hv1;  // m(e0)
        ins[wave][2*j + 1][lane] = agg[(size_t)s1 * DIM + lane] - hv0;  // m(e1)
      }
    }
    float acc[8] = {bl, bl, bl, bl, bl, bl, bl, bl};
    #pragma unroll
    for (int k4 = 0; k4 < 16; ++k4) {
      float4 iq[8];
      #pragma unroll
      for (int e = 0; e < 8; ++e) iq[e] = ((const float4*)ins[wave][e])[k4];
      const float w0 = wcol[4*k4], w1 = wcol[4*k4+1], w2 = wcol[4*k4+2], w3 = wcol[4*k4+3];
      #pragma unroll
      for (int e = 0; e < 8; ++e) acc[e] = fmaf(iq[e].x, w0, acc[e]);
      #pragma unroll
      for (int e = 0; e < 8; ++e) acc[e] = fmaf(iq[e].y, w1, acc[e]);
      #pragma unroll
      for (int e = 0; e < 8; ++e) acc[e] = fmaf(iq[e].z, w2, acc[e]);
      #pragma unroll
      for (int e = 0; e < 8; ++e) acc[e] = fmaf(iq[e].w, w3, acc[e]);
    }
    #pragma unroll
    for (int j = 0; j < 4; ++j) {
      const int p = base + j;
      if (p < P) {
        const size_t e0 = (size_t)2 * p;
        const float v0 = fmaxf(h0[e0 * DIM + lane] + acc[2*j], 0.0f);
        const float v1 = fmaxf(h0[e0 * DIM + DIM + lane] + acc[2*j + 1], 0.0f);
        hout[e0 * DIM + lane]       = v0;
        hout[e0 * DIM + DIM + lane] = v1;
        // dst(e0)=src(e1)=s1 ; dst(e1)=src(e0)=s0
        atomicAdd(&aggN[(size_t)s1a[j] * DIM + lane], v0);
        atomicAdd(&aggN[(size_t)s0a[j] * DIM + lane], v1);
      }
    }
  }
}

// ---- readout: node_out[n] = relu([nf[n]||agg[n]] @ W_proj + b) ----
__global__ __launch_bounds__(256) void k_readout(
    const float* __restrict__ nf, const float* __restrict__ agg,
    const float* __restrict__ W, const float* __restrict__ b,
    float* __restrict__ out, int N) {
  __shared__ float ins[4][4][2 * DIM];
  const int tid = threadIdx.x, wave = tid >> 6, lane = tid & 63;
  float wcol[128];
  #pragma unroll
  for (int k = 0; k < 128; ++k) wcol[k] = W[k * 64 + lane];
  const float bl = b[lane];
  for (int base = blockIdx.x * 16 + wave * 4; base < N; base += gridDim.x * 16) {
    #pragma unroll
    for (int j = 0; j < 4; ++j) {
      const int n = base + j;
      if (n < N) {
        ins[wave][j][lane]       = nf[(size_t)n * DIM + lane];
        ins[wave][j][DIM + lane] = agg[(size_t)n * DIM + lane];
      }
    }
    float acc[4] = {bl, bl, bl, bl};
    const float4* q0 = (const float4*)ins[wave][0];
    const float4* q1 = (const float4*)ins[wave][1];
    const float4* q2 = (const float4*)ins[wave][2];
    const float4* q3 = (const float4*)ins[wave][3];
    #pragma unroll
    for (int k4 = 0; k4 < 32; ++k4) {
      const float4 i0 = q0[k4], i1 = q1[k4], i2 = q2[k4], i3 = q3[k4];
      const float w0 = wcol[4*k4], w1 = wcol[4*k4+1], w2 = wcol[4*k4+2], w3 = wcol[4*k4+3];
      acc[0] = fmaf(i0.x, w0, acc[0]); acc[1] = fmaf(i1.x, w0, acc[1]);
      acc[2] = fmaf(i2.x, w0, acc[2]); acc[3] = fmaf(i3.x, w0, acc[3]);
      acc[0] = fmaf(i0.y, w1, acc[0]); acc[1] = fmaf(i1.y, w1, acc[1]);
      acc[2] = fmaf(i2.y, w1, acc[2]); acc[3] = fmaf(i3.y, w1, acc[3]);
      acc[0] = fmaf(i0.z, w2, acc[0]); acc[1] = fmaf(i1.z, w2, acc[1]);
      acc[2] = fmaf(i2.z, w2, acc[2]); acc[3] = fmaf(i3.z, w2, acc[3]);
      acc[0] = fmaf(i0.w, w3, acc[0]); acc[1] = fmaf(i1.w, w3, acc[1]);
      acc[2] = fmaf(i2.w, w3, acc[2]); acc[3] = fmaf(i3.w, w3, acc[3]);
    }
    #pragma unroll
    for (int j = 0; j < 4; ++j) {
      const int n = base + j;
      if (n < N) out[(size_t)n * DIM + lane] = fmaxf(acc[j], 0.0f);
    }
  }
}

extern "C" void kernel_launch(void* const* d_in, const int* in_sizes, int n_in,
                              void* d_out, int out_size, void* d_ws, size_t ws_size,
                              hipStream_t stream) {
  const float* nf     = (const float*)d_in[0];
  const float* ef     = (const float*)d_in[1];
  const int*   src    = (const int*)d_in[2];
  const int*   dst    = (const int*)d_in[3];
  const float* W_init = (const float*)d_in[5];
  const float* b_init = (const float*)d_in[6];
  const float* W_st   = (const float*)d_in[7];
  const float* b_st   = (const float*)d_in[8];
  const float* W_proj = (const float*)d_in[9];
  const float* b_proj = (const float*)d_in[10];

  const int N = in_sizes[0] / DIM;
  const int E = in_sizes[2];
  const int STEPS = in_sizes[7] / (DIM * DIM);

  float* node_out = (float*)d_out;
  float* h        = (float*)d_out + (size_t)N * DIM;
  float* aggA     = (float*)d_ws;
  float* aggB     = (float*)d_ws + (size_t)N * DIM;
  float* h0       = (float*)d_ws + (size_t)2 * N * DIM;

  const size_t aggBytes = (size_t)N * DIM * sizeof(float);

  hipMemsetAsync(aggA, 0, aggBytes, stream);
  hipMemsetAsync(aggB, 0, aggBytes, stream);
  k_init<<<2048, 256, 0, stream>>>(nf, ef, src, dst, W_init, b_init, h0, aggA, E);

  float* rd = aggA;
  float* wr = aggB;
  for (int t = 0; t < STEPS; ++t) {
    if (t > 0) hipMemsetAsync(wr, 0, aggBytes, stream);
    const float* hin = (t == 0) ? h0 : h;  // h_0 == h0; init skips writing h
    k_step<<<2048, 256, 0, stream>>>(rd, src, h0,
                                     W_st + (size_t)t * DIM * DIM,
                                     b_st + (size_t)t * DIM,
                                     hin, h, wr, E);
    float* tmp = rd; rd = wr; wr = tmp;
  }
  k_readout<<<1024, 256, 0, stream>>>(nf, rd, W_proj, b_proj, node_out, N);
}